// Round 9
// baseline (106.906 us; speedup 1.0000x reference)
//
#include <hip/hip_runtime.h>
#include <hip/hip_bf16.h>

// SelfAttentionBlock: B=4, C=256, RC=128, H=W=64 (N=4096)
// Round 9: k_attn frozen at the round-8-verified version (76us). Occupancy fixes
// for the projection kernels: k_qkv QBLK 64->32 (grid 512, 2 blocks/CU),
// k_out CBLK 128->64 (grid 1024, 4 blocks/CU).

#define B_   4
#define C_   256
#define RC_  128
#define N_   4096
#define SCALEL 0.12750880597462906f                // (1/sqrt(128)) * log2(e)

typedef __bf16 bf16x8 __attribute__((ext_vector_type(8)));
typedef unsigned short u16x8 __attribute__((ext_vector_type(8)));
typedef float f32x4 __attribute__((ext_vector_type(4)));

static __device__ __forceinline__ unsigned short f2bf(float f) {
    unsigned int u = __builtin_bit_cast(unsigned int, f);
    u += 0x7fffu + ((u >> 16) & 1u);
    return (unsigned short)(u >> 16);
}

static __device__ __forceinline__ f32x4 mfma16(u16x8 a, u16x8 b, f32x4 c) {
    return __builtin_amdgcn_mfma_f32_16x16x32_bf16(
        __builtin_bit_cast(bf16x8, a), __builtin_bit_cast(bf16x8, b), c, 0, 0, 0);
}

static __device__ __forceinline__ unsigned int cvtpk(float lo, float hi) {
    unsigned int r;
    asm("v_cvt_pk_bf16_f32 %0, %1, %2" : "=v"(r) : "v"(lo), "v"(hi));
    return r;   // low 16 = bf16(lo), high 16 = bf16(hi), RNE
}

static __device__ __forceinline__ void gl_lds16(const void* g, void* l) {
    __builtin_amdgcn_global_load_lds(
        (const __attribute__((address_space(1))) void*)g,
        (__attribute__((address_space(3))) void*)l, 16, 0, 0);
}

// ---------------- kernel 0: convert weights to bf16 ----------------
__global__ __launch_bounds__(256) void k_cvtw(
    const float* __restrict__ wq, const float* __restrict__ wk,
    const float* __restrict__ wv, const float* __restrict__ wo,
    unsigned short* __restrict__ ws)
{
    int i = blockIdx.x * 256 + threadIdx.x;  // 0..131071
    const float* src; int off;
    if (i < 32768)       { src = wq; off = 0; }
    else if (i < 65536)  { src = wk; off = 32768; }
    else if (i < 98304)  { src = wv; off = 65536; }
    else                 { src = wo; off = 98304; }
    int j = i - off;
    ws[off + j] = f2bf(src[j]);
}

// ---------------- kernel 1: QKV projection (QBLK=32, 2 blocks/CU) ----------------
// Same verified fragment mappings as round 8, token-tile halved.
// V epilogue stores the per-tile LDS image: Vt[tile][d=r][36] with in-row
// position p = g*8 + nf*4 + i for key k = nf*16 + g*4 + i.
#define K1_LDA 264  // 256 + 8 pad (shorts)

__global__ __launch_bounds__(256) void k_qkv(
    const float* __restrict__ x, const unsigned short* __restrict__ wbf,
    const float* __restrict__ bq, const float* __restrict__ bk, const float* __restrict__ bv,
    unsigned short* __restrict__ Qb, unsigned short* __restrict__ Kb,
    unsigned short* __restrict__ Vt)
{
    __shared__ unsigned short lds[32 * K1_LDA];   // 16.9 KB
    const int b  = blockIdx.y;
    const int n0 = blockIdx.x * 32;
    const int t  = threadIdx.x;
    const int lane = t & 63, wv_ = t >> 6;
    const int g = lane >> 4, q16 = lane & 15;

    // stage x[b][c][n0+tok] -> lds[tok][c]: thread t covers token t&31, c-range (t>>5)*32
    {
        int tok = t & 31;
        int cb  = (t >> 5) * 32;
        const float* xb = x + ((size_t)b * C_ * N_) + n0 + tok;
        #pragma unroll
        for (int it = 0; it < 4; ++it) {
            int c0 = cb + it * 8;
            u16x8 v;
            #pragma unroll
            for (int e = 0; e < 8; ++e)
                v[e] = f2bf(xb[(size_t)(c0 + e) * N_]);
            *(u16x8*)&lds[tok * K1_LDA + c0] = v;
        }
    }
    __syncthreads();

    f32x4 acc[3][2][2];   // [tq][r2][nf]
    #pragma unroll
    for (int tq = 0; tq < 3; ++tq)
        #pragma unroll
        for (int r2 = 0; r2 < 2; ++r2)
            #pragma unroll
            for (int nf = 0; nf < 2; ++nf)
                acc[tq][r2][nf] = (f32x4){0.f, 0.f, 0.f, 0.f};

    const int rbase = wv_ * 32;
    #pragma unroll
    for (int ks = 0; ks < 8; ++ks) {
        u16x8 a[2];
        #pragma unroll
        for (int nf = 0; nf < 2; ++nf)
            a[nf] = *(const u16x8*)&lds[(nf * 16 + q16) * K1_LDA + ks * 32 + g * 8];
        #pragma unroll
        for (int tq = 0; tq < 3; ++tq) {
            const unsigned short* w = wbf + tq * 32768;
            #pragma unroll
            for (int r2 = 0; r2 < 2; ++r2) {
                u16x8 bf = *(const u16x8*)&w[(size_t)(rbase + r2 * 16 + q16) * 256 + ks * 32 + g * 8];
                #pragma unroll
                for (int nf = 0; nf < 2; ++nf)
                    acc[tq][r2][nf] = mfma16(a[nf], bf, acc[tq][r2][nf]);
            }
        }
    }

    #pragma unroll
    for (int r2 = 0; r2 < 2; ++r2) {
        int r = rbase + r2 * 16 + q16;
        float biasq = bq[r], biask = bk[r];
        #pragma unroll
        for (int nf = 0; nf < 2; ++nf) {
            #pragma unroll
            for (int i = 0; i < 4; ++i) {
                int n = n0 + nf * 16 + g * 4 + i;
                size_t idx = ((size_t)b * N_ + n) * RC_ + r;
                Qb[idx] = f2bf((acc[0][r2][nf][i] + biasq) * SCALEL);
                Kb[idx] = f2bf(acc[1][r2][nf][i] + biask);
            }
        }
    }

    // V direct store in image layout (stride 36 shorts); this block = one key-tile.
    const size_t tile = (size_t)b * 128 + blockIdx.x;
    #pragma unroll
    for (int r2 = 0; r2 < 2; ++r2) {
        int r = rbase + r2 * 16 + q16;
        float biasv = bv[r];
        #pragma unroll
        for (int nf = 0; nf < 2; ++nf) {
            unsigned int w0 = (unsigned int)f2bf(acc[2][r2][nf][0] + biasv)
                            | ((unsigned int)f2bf(acc[2][r2][nf][1] + biasv) << 16);
            unsigned int w1 = (unsigned int)f2bf(acc[2][r2][nf][2] + biasv)
                            | ((unsigned int)f2bf(acc[2][r2][nf][3] + biasv) << 16);
            unsigned short* dst = Vt + (tile * 128 + r) * 36 + g * 8 + nf * 4;
            *(uint2*)dst = make_uint2(w0, w1);
        }
    }
}

// ---------------- kernel 2: flash attention (round-8 verified, frozen) ----------------
// 16 waves: qw = wv&1 (32 q-rows), grp = wv>>1 (512 keys, 16 tiles of 32).
// smem (shorts): Q [0,8192) 64x128 XOR-swz; K @8192+grp*4096: [32][128] XOR-swz (DMA);
//                V @40960+grp*4608: [128][36] image (linear DMA copy).
// merge overlay: l f32 @ [0,1024); U bf16 8x[64][132] @ [8192, 75776).
__global__ __launch_bounds__(1024, 4) void k_attn(
    const unsigned short* __restrict__ Qb, const unsigned short* __restrict__ Kb,
    const unsigned short* __restrict__ Vt, unsigned short* __restrict__ Ob)
{
    __shared__ __align__(16) unsigned short smem[77824];   // 152 KiB
    const int b  = blockIdx.y;
    const int n0 = blockIdx.x * 64;
    const int t  = threadIdx.x;
    const int lane = t & 63, wv_ = t >> 6;        // 16 waves
    const int qw = wv_ & 1, grp = wv_ >> 1;       // 8 KV groups
    const int g = lane >> 4, q16 = lane & 15;

    unsigned short* Ql = smem;
    unsigned short* Kl = smem + 8192 + grp * 4096;
    unsigned short* Vl = smem + 40960 + grp * 4608;

    const unsigned short* Qg = Qb + ((size_t)b * N_ + n0) * RC_;
    const unsigned short* Kg = Kb + ((size_t)b * N_ + grp * 512) * RC_;
    const unsigned short* Vg = Vt + ((size_t)b * 128 + grp * 16) * 4608;

    // ---- Q stage: register path + XOR-swizzled ds_write ----
    {
        int sq = wv_ * 64 + lane;                 // 0..1023
        int row = sq >> 4, ch = sq & 15;
        uint4 v = *(const uint4*)&Qg[(size_t)row * RC_ + ch * 8];
        *(uint4*)&Ql[row * 128 + ((ch ^ (row & 7)) * 8)] = v;
    }

    // ---- DMA staging: wave-uniform LDS dest + per-lane (pre-swizzled) source ----
    #define STAGEK(kt_) do { int ktc = (kt_);                                    \
        _Pragma("unroll")                                                        \
        for (int r = 0; r < 4; ++r) {                                            \
            int m = qw * 4 + r;                                                  \
            int row = m * 4 + (lane >> 4);                                       \
            int ch = (lane & 15) ^ (row & 7);                                    \
            gl_lds16(Kg + (size_t)(ktc * 32 + row) * RC_ + ch * 8,               \
                     (char*)Kl + m * 1024);                                      \
        }                                                                        \
    } while (0)
    #define STAGEV(kt_) do { int ktc = (kt_);                                    \
        const char* vsrc = (const char*)(Vg + (size_t)ktc * 4608);               \
        char* vdst = (char*)Vl;                                                  \
        _Pragma("unroll")                                                        \
        for (int j = 0; j < 4; ++j) {                                            \
            int off = j * 2048 + qw * 1024;                                      \
            gl_lds16(vsrc + off + lane * 16, vdst + off);                        \
        }                                                                        \
        if (qw == 0)                                                             \
            gl_lds16(vsrc + 8192 + lane * 16, vdst + 8192);                      \
    } while (0)

    STAGEK(0);
    STAGEV(0);

    f32x4 acc_o[2][8];
    #pragma unroll
    for (int rf = 0; rf < 2; ++rf)
        #pragma unroll
        for (int df = 0; df < 8; ++df)
            acc_o[rf][df] = (f32x4){0.f, 0.f, 0.f, 0.f};
    float l_loc[2] = {0.f, 0.f};

    __syncthreads();   // Q ds_write + K/V DMA drained

    for (int kt = 0; kt < 16; ++kt) {
        // S^T = K Q^T (swapped): lane holds S[q = qblock + q16][k = kf*16 + g*4 + i]
        f32x4 s[2][2];
        #pragma unroll
        for (int rf = 0; rf < 2; ++rf)
            #pragma unroll
            for (int kf = 0; kf < 2; ++kf)
                s[rf][kf] = (f32x4){0.f, 0.f, 0.f, 0.f};
        __builtin_amdgcn_s_setprio(1);
        #pragma unroll
        for (int ks = 0; ks < 4; ++ks) {
            int sw = ((4 * ks + g) ^ (q16 & 7)) * 8;
            u16x8 qf0 = *(const u16x8*)&Ql[(qw * 32 + q16) * 128 + sw];
            u16x8 qf1 = *(const u16x8*)&Ql[(qw * 32 + 16 + q16) * 128 + sw];
            #pragma unroll
            for (int kf = 0; kf < 2; ++kf) {
                u16x8 kfr = *(const u16x8*)&Kl[(kf * 16 + q16) * 128 + sw];
                s[0][kf] = mfma16(kfr, qf0, s[0][kf]);
                s[1][kf] = mfma16(kfr, qf1, s[1][kf]);
            }
        }
        __builtin_amdgcn_s_setprio(0);

        // no-max softmax: p = exp2(S') (log2e folded into Q); pack P via cvt_pk
        u16x8 pa[2];
        #pragma unroll
        for (int rf = 0; rf < 2; ++rf) {
            #pragma unroll
            for (int kf = 0; kf < 2; ++kf)
                #pragma unroll
                for (int i = 0; i < 4; ++i)
                    s[rf][kf][i] = exp2f(s[rf][kf][i]);
            l_loc[rf] += (s[rf][0][0] + s[rf][0][1]) + (s[rf][0][2] + s[rf][0][3])
                       + (s[rf][1][0] + s[rf][1][1]) + (s[rf][1][2] + s[rf][1][3]);
            int4 pk;
            pk.x = (int)cvtpk(s[rf][0][0], s[rf][0][1]);
            pk.y = (int)cvtpk(s[rf][0][2], s[rf][0][3]);
            pk.z = (int)cvtpk(s[rf][1][0], s[rf][1][1]);
            pk.w = (int)cvtpk(s[rf][1][2], s[rf][1][3]);
            pa[rf] = __builtin_bit_cast(u16x8, pk);
        }

        // O += P @ V.  V image row d: lane's 8 B-slots contiguous at short offset
        // g*8, read as two 8B chunks (stride 72B not 16B-aligned for odd d).
        __builtin_amdgcn_s_setprio(1);
        #pragma unroll
        for (int df = 0; df < 8; ++df) {
            int d = df * 16 + q16;
            const unsigned short* vrow = &Vl[d * 36 + g * 8];
            uint2 vlo = *(const uint2*)&vrow[0];
            uint2 vhi = *(const uint2*)&vrow[4];
            int4 vv = make_int4((int)vlo.x, (int)vlo.y, (int)vhi.x, (int)vhi.y);
            u16x8 vb = __builtin_bit_cast(u16x8, vv);
            acc_o[0][df] = mfma16(pa[0], vb, acc_o[0][df]);
            acc_o[1][df] = mfma16(pa[1], vb, acc_o[1][df]);
        }
        __builtin_amdgcn_s_setprio(0);

        __syncthreads();              // all reads of tile kt done
        if (kt < 15) {
            STAGEK(kt + 1);           // DMA next K tile
            STAGEV(kt + 1);           // DMA next V tile (linear image copy)
        }
        __syncthreads();              // DMA drained
    }

    // ---- merge across 8 KV groups ----
    float l0 = l_loc[0], l1 = l_loc[1];
    l0 += __shfl_xor(l0, 16); l0 += __shfl_xor(l0, 32);
    l1 += __shfl_xor(l1, 16); l1 += __shfl_xor(l1, 32);

    float* lf = (float*)smem;                       // [8 grp][64 rows]
    unsigned short* Ub = smem + 8192;               // [8 grp][64][132] bf16
    if (g == 0) {
        lf[grp * 64 + qw * 32 + q16]      = l0;
        lf[grp * 64 + qw * 32 + 16 + q16] = l1;
    }
    {
        unsigned short* Ug = Ub + grp * 8448;
        #pragma unroll
        for (int rf = 0; rf < 2; ++rf)
            #pragma unroll
            for (int df = 0; df < 8; ++df)
                #pragma unroll
                for (int i = 0; i < 4; ++i)
                    Ug[(qw * 32 + rf * 16 + g * 4 + i) * 132 + df * 16 + q16] =
                        f2bf(acc_o[rf][df][i]);
    }
    __syncthreads();

    // combine: wave wv_ handles q-rows [wv_*4, wv_*4+4), lane covers 2 d-cols
    #pragma unroll
    for (int r = 0; r < 4; ++r) {
        int row = wv_ * 4 + r;
        float lt = 0.f;
        #pragma unroll
        for (int gg = 0; gg < 8; ++gg) lt += lf[gg * 64 + row];
        float inv = 1.f / lt;
        float o0 = 0.f, o1 = 0.f;
        #pragma unroll
        for (int gg = 0; gg < 8; ++gg) {
            unsigned int u = *(const unsigned int*)&Ub[gg * 8448 + row * 132 + lane * 2];
            o0 += __builtin_bit_cast(float, u << 16);
            o1 += __builtin_bit_cast(float, u & 0xffff0000u);
        }
        unsigned int packed = ((unsigned int)f2bf(o1 * inv) << 16) | f2bf(o0 * inv);
        *(unsigned int*)&Ob[((size_t)b * N_ + n0 + row) * RC_ + lane * 2] = packed;
    }
    #undef STAGEK
    #undef STAGEV
}

// ---------------- kernel 3: output projection + residual (CBLK=64, 4 blocks/CU) ----------------
#define QS 136  // 128 + 8 pad (shorts)

__global__ __launch_bounds__(256) void k_out(
    const unsigned short* __restrict__ Ob, const unsigned short* __restrict__ wobf,
    const float* __restrict__ bo, const float* __restrict__ x,
    const float* __restrict__ gamma, float* __restrict__ out)
{
    __shared__ unsigned short Ol[64 * QS];
    const int b  = blockIdx.z;
    const int c0 = blockIdx.y * 64;
    const int n0 = blockIdx.x * 64;
    const int t  = threadIdx.x;
    const int lane = t & 63, wv_ = t >> 6;
    const int g = lane >> 4, q16 = lane & 15;

    {
        const unsigned short* src = Ob + ((size_t)b * N_ + n0) * RC_;
        #pragma unroll
        for (int p = 0; p < 4; ++p) {
            int row = p * 16 + (t >> 4);
            int s = (t & 15) * 8;
            *(u16x8*)&Ol[row * QS + s] = *(const u16x8*)&src[row * RC_ + s];
        }
    }
    __syncthreads();

    f32x4 acc[4];
    #pragma unroll
    for (int nf = 0; nf < 4; ++nf)
        acc[nf] = (f32x4){0.f, 0.f, 0.f, 0.f};

    const int cw = c0 + wv_ * 16;
    #pragma unroll
    for (int ks = 0; ks < 4; ++ks) {
        u16x8 b8[4];
        #pragma unroll
        for (int nf = 0; nf < 4; ++nf)
            b8[nf] = *(const u16x8*)&Ol[(nf * 16 + q16) * QS + ks * 32 + g * 8];
        u16x8 a8 = *(const u16x8*)&wobf[(size_t)(cw + q16) * 128 + ks * 32 + g * 8];
        #pragma unroll
        for (int nf = 0; nf < 4; ++nf)
            acc[nf] = mfma16(a8, b8[nf], acc[nf]);
    }

    float gm = gamma[0];
    #pragma unroll
    for (int i = 0; i < 4; ++i) {
        int c = cw + g * 4 + i;
        float bias = bo[c];
        #pragma unroll
        for (int nf = 0; nf < 4; ++nf) {
            int n = n0 + nf * 16 + q16;
            size_t idx = ((size_t)b * C_ + c) * N_ + n;
            out[idx] = gm * (acc[nf][i] + bias) + x[idx];
        }
    }
}

extern "C" void kernel_launch(void* const* d_in, const int* in_sizes, int n_in,
                              void* d_out, int out_size, void* d_ws, size_t ws_size,
                              hipStream_t stream) {
    const float* x     = (const float*)d_in[0];
    const float* wq    = (const float*)d_in[1];
    const float* bq    = (const float*)d_in[2];
    const float* wk    = (const float*)d_in[3];
    const float* bk    = (const float*)d_in[4];
    const float* wv    = (const float*)d_in[5];
    const float* bv    = (const float*)d_in[6];
    const float* wo    = (const float*)d_in[7];
    const float* bo    = (const float*)d_in[8];
    const float* gamma = (const float*)d_in[9];
    float* out = (float*)d_out;

    unsigned short* ws = (unsigned short*)d_ws;
    unsigned short* wbf  = ws;                 // wq,wk,wv (3*32768), wo at +98304
    unsigned short* wobf = ws + 98304;
    unsigned short* Qb   = ws + 131072;        // [B][N][RC] bf16 (also reused as Ob)
    unsigned short* Kb   = Qb + 2097152;       // [B][N][RC] bf16
    unsigned short* Vt   = Kb + 2097152;       // [B*128 tiles][128][36] image
    unsigned short* Ob   = Qb;                 // alias: k_attn reads Q only in prologue

    k_cvtw<<<512, 256, 0, stream>>>(wq, wk, wv, wo, ws);
    dim3 g1(128, 4);
    k_qkv<<<g1, 256, 0, stream>>>(x, wbf, bq, bk, bv, Qb, Kb, Vt);
    dim3 g2(64, 4);
    k_attn<<<g2, 1024, 0, stream>>>(Qb, Kb, Vt, Ob);
    dim3 g3(64, 4, 4);
    k_out<<<g3, 256, 0, stream>>>(Ob, wobf, bo, x, gamma, out);
}

// Round 10
// 98.764 us; speedup vs baseline: 1.0824x; 1.0824x over previous
//
#include <hip/hip_runtime.h>
#include <hip/hip_bf16.h>

// SelfAttentionBlock: B=4, C=256, RC=128, H=W=64 (N=4096)
// Round 10:
//  (1) k_attn: split-issue DMA staging — STAGEK(kt+1) issued right after the
//      post-QK barrier (hides under softmax+PV), STAGEV(kt+1) after the post-PV
//      barrier (hides under next QK). Same barriers/buffers; pure reorder.
//  (2) k_cvtw eliminated: k_qkv/k_out convert f32 weights inline via cvt_pk.

#define B_   4
#define C_   256
#define RC_  128
#define N_   4096
#define SCALEL 0.12750880597462906f                // (1/sqrt(128)) * log2(e)

typedef __bf16 bf16x8 __attribute__((ext_vector_type(8)));
typedef unsigned short u16x8 __attribute__((ext_vector_type(8)));
typedef float f32x4 __attribute__((ext_vector_type(4)));

static __device__ __forceinline__ unsigned short f2bf(float f) {
    unsigned int u = __builtin_bit_cast(unsigned int, f);
    u += 0x7fffu + ((u >> 16) & 1u);
    return (unsigned short)(u >> 16);
}

static __device__ __forceinline__ f32x4 mfma16(u16x8 a, u16x8 b, f32x4 c) {
    return __builtin_amdgcn_mfma_f32_16x16x32_bf16(
        __builtin_bit_cast(bf16x8, a), __builtin_bit_cast(bf16x8, b), c, 0, 0, 0);
}

static __device__ __forceinline__ unsigned int cvtpk(float lo, float hi) {
    unsigned int r;
    asm("v_cvt_pk_bf16_f32 %0, %1, %2" : "=v"(r) : "v"(lo), "v"(hi));
    return r;   // low 16 = bf16(lo), high 16 = bf16(hi), RNE
}

// load 8 consecutive f32 weights and pack to bf16x8 (same RNE as f2bf)
static __device__ __forceinline__ u16x8 ldw8(const float* p) {
    float4 f0 = *(const float4*)p;
    float4 f1 = *(const float4*)(p + 4);
    int4 pk;
    pk.x = (int)cvtpk(f0.x, f0.y);
    pk.y = (int)cvtpk(f0.z, f0.w);
    pk.z = (int)cvtpk(f1.x, f1.y);
    pk.w = (int)cvtpk(f1.z, f1.w);
    return __builtin_bit_cast(u16x8, pk);
}

static __device__ __forceinline__ void gl_lds16(const void* g, void* l) {
    __builtin_amdgcn_global_load_lds(
        (const __attribute__((address_space(1))) void*)g,
        (__attribute__((address_space(3))) void*)l, 16, 0, 0);
}

// ---------------- kernel 1: QKV projection (QBLK=32, inline weight cvt) ----------------
// V epilogue stores the per-tile LDS image: Vt[tile][d=r][36] with in-row
// position p = g*8 + nf*4 + i for key k = nf*16 + g*4 + i.
#define K1_LDA 264  // 256 + 8 pad (shorts)

__global__ __launch_bounds__(256) void k_qkv(
    const float* __restrict__ x,
    const float* __restrict__ wq, const float* __restrict__ wk, const float* __restrict__ wv,
    const float* __restrict__ bq, const float* __restrict__ bk, const float* __restrict__ bv,
    unsigned short* __restrict__ Qb, unsigned short* __restrict__ Kb,
    unsigned short* __restrict__ Vt)
{
    __shared__ unsigned short lds[32 * K1_LDA];   // 16.9 KB
    const int b  = blockIdx.y;
    const int n0 = blockIdx.x * 32;
    const int t  = threadIdx.x;
    const int lane = t & 63, wv_ = t >> 6;
    const int g = lane >> 4, q16 = lane & 15;

    // stage x[b][c][n0+tok] -> lds[tok][c]
    {
        int tok = t & 31;
        int cb  = (t >> 5) * 32;
        const float* xb = x + ((size_t)b * C_ * N_) + n0 + tok;
        #pragma unroll
        for (int it = 0; it < 4; ++it) {
            int c0 = cb + it * 8;
            u16x8 v;
            #pragma unroll
            for (int e = 0; e < 8; ++e)
                v[e] = f2bf(xb[(size_t)(c0 + e) * N_]);
            *(u16x8*)&lds[tok * K1_LDA + c0] = v;
        }
    }
    __syncthreads();

    f32x4 acc[3][2][2];   // [tq][r2][nf]
    #pragma unroll
    for (int tq = 0; tq < 3; ++tq)
        #pragma unroll
        for (int r2 = 0; r2 < 2; ++r2)
            #pragma unroll
            for (int nf = 0; nf < 2; ++nf)
                acc[tq][r2][nf] = (f32x4){0.f, 0.f, 0.f, 0.f};

    const float* wsrc[3] = {wq, wk, wv};
    const int rbase = wv_ * 32;
    #pragma unroll
    for (int ks = 0; ks < 8; ++ks) {
        u16x8 a[2];
        #pragma unroll
        for (int nf = 0; nf < 2; ++nf)
            a[nf] = *(const u16x8*)&lds[(nf * 16 + q16) * K1_LDA + ks * 32 + g * 8];
        #pragma unroll
        for (int tq = 0; tq < 3; ++tq) {
            const float* w = wsrc[tq];
            #pragma unroll
            for (int r2 = 0; r2 < 2; ++r2) {
                u16x8 bf = ldw8(&w[(size_t)(rbase + r2 * 16 + q16) * 256 + ks * 32 + g * 8]);
                #pragma unroll
                for (int nf = 0; nf < 2; ++nf)
                    acc[tq][r2][nf] = mfma16(a[nf], bf, acc[tq][r2][nf]);
            }
        }
    }

    #pragma unroll
    for (int r2 = 0; r2 < 2; ++r2) {
        int r = rbase + r2 * 16 + q16;
        float biasq = bq[r], biask = bk[r];
        #pragma unroll
        for (int nf = 0; nf < 2; ++nf) {
            #pragma unroll
            for (int i = 0; i < 4; ++i) {
                int n = n0 + nf * 16 + g * 4 + i;
                size_t idx = ((size_t)b * N_ + n) * RC_ + r;
                Qb[idx] = f2bf((acc[0][r2][nf][i] + biasq) * SCALEL);
                Kb[idx] = f2bf(acc[1][r2][nf][i] + biask);
            }
        }
    }

    // V direct store in image layout (stride 36 shorts); this block = one key-tile.
    const size_t tile = (size_t)b * 128 + blockIdx.x;
    #pragma unroll
    for (int r2 = 0; r2 < 2; ++r2) {
        int r = rbase + r2 * 16 + q16;
        float biasv = bv[r];
        #pragma unroll
        for (int nf = 0; nf < 2; ++nf) {
            unsigned int w0 = (unsigned int)f2bf(acc[2][r2][nf][0] + biasv)
                            | ((unsigned int)f2bf(acc[2][r2][nf][1] + biasv) << 16);
            unsigned int w1 = (unsigned int)f2bf(acc[2][r2][nf][2] + biasv)
                            | ((unsigned int)f2bf(acc[2][r2][nf][3] + biasv) << 16);
            unsigned short* dst = Vt + (tile * 128 + r) * 36 + g * 8 + nf * 4;
            *(uint2*)dst = make_uint2(w0, w1);
        }
    }
}

// ---------------- kernel 2: flash attention (split-issue DMA staging) ----------------
// 16 waves: qw = wv&1 (32 q-rows), grp = wv>>1 (512 keys, 16 tiles of 32).
// smem (shorts): Q [0,8192) 64x128 XOR-swz; K @8192+grp*4096: [32][128] XOR-swz (DMA);
//                V @40960+grp*4608: [128][36] image (linear DMA copy).
// merge overlay: l f32 @ [0,1024); U bf16 8x[64][132] @ [8192, 75776).
// Schedule per iter: QK | barrier A (drains V-DMA) | issue STAGEK(kt+1) |
//                    softmax | PV | barrier B (drains K-DMA) | issue STAGEV(kt+1)
__global__ __launch_bounds__(1024, 4) void k_attn(
    const unsigned short* __restrict__ Qb, const unsigned short* __restrict__ Kb,
    const unsigned short* __restrict__ Vt, unsigned short* __restrict__ Ob)
{
    __shared__ __align__(16) unsigned short smem[77824];   // 152 KiB
    const int b  = blockIdx.y;
    const int n0 = blockIdx.x * 64;
    const int t  = threadIdx.x;
    const int lane = t & 63, wv_ = t >> 6;        // 16 waves
    const int qw = wv_ & 1, grp = wv_ >> 1;       // 8 KV groups
    const int g = lane >> 4, q16 = lane & 15;

    unsigned short* Ql = smem;
    unsigned short* Kl = smem + 8192 + grp * 4096;
    unsigned short* Vl = smem + 40960 + grp * 4608;

    const unsigned short* Qg = Qb + ((size_t)b * N_ + n0) * RC_;
    const unsigned short* Kg = Kb + ((size_t)b * N_ + grp * 512) * RC_;
    const unsigned short* Vg = Vt + ((size_t)b * 128 + grp * 16) * 4608;

    // ---- Q stage: register path + XOR-swizzled ds_write ----
    {
        int sq = wv_ * 64 + lane;                 // 0..1023
        int row = sq >> 4, ch = sq & 15;
        uint4 v = *(const uint4*)&Qg[(size_t)row * RC_ + ch * 8];
        *(uint4*)&Ql[row * 128 + ((ch ^ (row & 7)) * 8)] = v;
    }

    // ---- DMA staging: wave-uniform LDS dest + per-lane (pre-swizzled) source ----
    #define STAGEK(kt_) do { int ktc = (kt_);                                    \
        _Pragma("unroll")                                                        \
        for (int r = 0; r < 4; ++r) {                                            \
            int m = qw * 4 + r;                                                  \
            int row = m * 4 + (lane >> 4);                                       \
            int ch = (lane & 15) ^ (row & 7);                                    \
            gl_lds16(Kg + (size_t)(ktc * 32 + row) * RC_ + ch * 8,               \
                     (char*)Kl + m * 1024);                                      \
        }                                                                        \
    } while (0)
    #define STAGEV(kt_) do { int ktc = (kt_);                                    \
        const char* vsrc = (const char*)(Vg + (size_t)ktc * 4608);               \
        char* vdst = (char*)Vl;                                                  \
        _Pragma("unroll")                                                        \
        for (int j = 0; j < 4; ++j) {                                            \
            int off = j * 2048 + qw * 1024;                                      \
            gl_lds16(vsrc + off + lane * 16, vdst + off);                        \
        }                                                                        \
        if (qw == 0)                                                             \
            gl_lds16(vsrc + 8192 + lane * 16, vdst + 8192);                      \
    } while (0)

    STAGEK(0);
    STAGEV(0);

    f32x4 acc_o[2][8];
    #pragma unroll
    for (int rf = 0; rf < 2; ++rf)
        #pragma unroll
        for (int df = 0; df < 8; ++df)
            acc_o[rf][df] = (f32x4){0.f, 0.f, 0.f, 0.f};
    float l_loc[2] = {0.f, 0.f};

    __syncthreads();   // Q ds_write + initial K/V DMA drained

    for (int kt = 0; kt < 16; ++kt) {
        // S^T = K Q^T (swapped): lane holds S[q = qblock + q16][k = kf*16 + g*4 + i]
        f32x4 s[2][2];
        #pragma unroll
        for (int rf = 0; rf < 2; ++rf)
            #pragma unroll
            for (int kf = 0; kf < 2; ++kf)
                s[rf][kf] = (f32x4){0.f, 0.f, 0.f, 0.f};
        __builtin_amdgcn_s_setprio(1);
        #pragma unroll
        for (int ks = 0; ks < 4; ++ks) {
            int sw = ((4 * ks + g) ^ (q16 & 7)) * 8;
            u16x8 qf0 = *(const u16x8*)&Ql[(qw * 32 + q16) * 128 + sw];
            u16x8 qf1 = *(const u16x8*)&Ql[(qw * 32 + 16 + q16) * 128 + sw];
            #pragma unroll
            for (int kf = 0; kf < 2; ++kf) {
                u16x8 kfr = *(const u16x8*)&Kl[(kf * 16 + q16) * 128 + sw];
                s[0][kf] = mfma16(kfr, qf0, s[0][kf]);
                s[1][kf] = mfma16(kfr, qf1, s[1][kf]);
            }
        }
        __builtin_amdgcn_s_setprio(0);

        __syncthreads();              // A: all QK reads of Kl done; V-DMA drained
        if (kt < 15) STAGEK(kt + 1);  // K-DMA flies under softmax + PV

        // no-max softmax: p = exp2(S') (log2e folded into Q); pack P via cvt_pk
        u16x8 pa[2];
        #pragma unroll
        for (int rf = 0; rf < 2; ++rf) {
            #pragma unroll
            for (int kf = 0; kf < 2; ++kf)
                #pragma unroll
                for (int i = 0; i < 4; ++i)
                    s[rf][kf][i] = exp2f(s[rf][kf][i]);
            l_loc[rf] += (s[rf][0][0] + s[rf][0][1]) + (s[rf][0][2] + s[rf][0][3])
                       + (s[rf][1][0] + s[rf][1][1]) + (s[rf][1][2] + s[rf][1][3]);
            int4 pk;
            pk.x = (int)cvtpk(s[rf][0][0], s[rf][0][1]);
            pk.y = (int)cvtpk(s[rf][0][2], s[rf][0][3]);
            pk.z = (int)cvtpk(s[rf][1][0], s[rf][1][1]);
            pk.w = (int)cvtpk(s[rf][1][2], s[rf][1][3]);
            pa[rf] = __builtin_bit_cast(u16x8, pk);
        }

        // O += P @ V.  V image row d: lane's 8 B-slots contiguous at short offset
        // g*8, read as two 8B chunks (stride 72B not 16B-aligned for odd d).
        __builtin_amdgcn_s_setprio(1);
        #pragma unroll
        for (int df = 0; df < 8; ++df) {
            int d = df * 16 + q16;
            const unsigned short* vrow = &Vl[d * 36 + g * 8];
            uint2 vlo = *(const uint2*)&vrow[0];
            uint2 vhi = *(const uint2*)&vrow[4];
            int4 vv = make_int4((int)vlo.x, (int)vlo.y, (int)vhi.x, (int)vhi.y);
            u16x8 vb = __builtin_bit_cast(u16x8, vv);
            acc_o[0][df] = mfma16(pa[0], vb, acc_o[0][df]);
            acc_o[1][df] = mfma16(pa[1], vb, acc_o[1][df]);
        }
        __builtin_amdgcn_s_setprio(0);

        __syncthreads();              // B: all PV reads of Vl done; K-DMA drained
        if (kt < 15) STAGEV(kt + 1);  // V-DMA flies under next iter's QK
    }

    // ---- merge across 8 KV groups ----
    float l0 = l_loc[0], l1 = l_loc[1];
    l0 += __shfl_xor(l0, 16); l0 += __shfl_xor(l0, 32);
    l1 += __shfl_xor(l1, 16); l1 += __shfl_xor(l1, 32);

    float* lf = (float*)smem;                       // [8 grp][64 rows]
    unsigned short* Ub = smem + 8192;               // [8 grp][64][132] bf16
    if (g == 0) {
        lf[grp * 64 + qw * 32 + q16]      = l0;
        lf[grp * 64 + qw * 32 + 16 + q16] = l1;
    }
    {
        unsigned short* Ug = Ub + grp * 8448;
        #pragma unroll
        for (int rf = 0; rf < 2; ++rf)
            #pragma unroll
            for (int df = 0; df < 8; ++df)
                #pragma unroll
                for (int i = 0; i < 4; ++i)
                    Ug[(qw * 32 + rf * 16 + g * 4 + i) * 132 + df * 16 + q16] =
                        f2bf(acc_o[rf][df][i]);
    }
    __syncthreads();

    // combine: wave wv_ handles q-rows [wv_*4, wv_*4+4), lane covers 2 d-cols
    #pragma unroll
    for (int r = 0; r < 4; ++r) {
        int row = wv_ * 4 + r;
        float lt = 0.f;
        #pragma unroll
        for (int gg = 0; gg < 8; ++gg) lt += lf[gg * 64 + row];
        float inv = 1.f / lt;
        float o0 = 0.f, o1 = 0.f;
        #pragma unroll
        for (int gg = 0; gg < 8; ++gg) {
            unsigned int u = *(const unsigned int*)&Ub[gg * 8448 + row * 132 + lane * 2];
            o0 += __builtin_bit_cast(float, u << 16);
            o1 += __builtin_bit_cast(float, u & 0xffff0000u);
        }
        unsigned int packed = ((unsigned int)f2bf(o1 * inv) << 16) | f2bf(o0 * inv);
        *(unsigned int*)&Ob[((size_t)b * N_ + n0 + row) * RC_ + lane * 2] = packed;
    }
    #undef STAGEK
    #undef STAGEV
}

// ---------------- kernel 3: output projection + residual (inline weight cvt) ----------------
#define QS 136  // 128 + 8 pad (shorts)

__global__ __launch_bounds__(256) void k_out(
    const unsigned short* __restrict__ Ob, const float* __restrict__ wo,
    const float* __restrict__ bo, const float* __restrict__ x,
    const float* __restrict__ gamma, float* __restrict__ out)
{
    __shared__ unsigned short Ol[64 * QS];
    const int b  = blockIdx.z;
    const int c0 = blockIdx.y * 64;
    const int n0 = blockIdx.x * 64;
    const int t  = threadIdx.x;
    const int lane = t & 63, wv_ = t >> 6;
    const int g = lane >> 4, q16 = lane & 15;

    {
        const unsigned short* src = Ob + ((size_t)b * N_ + n0) * RC_;
        #pragma unroll
        for (int p = 0; p < 4; ++p) {
            int row = p * 16 + (t >> 4);
            int s = (t & 15) * 8;
            *(u16x8*)&Ol[row * QS + s] = *(const u16x8*)&src[row * RC_ + s];
        }
    }
    __syncthreads();

    f32x4 acc[4];
    #pragma unroll
    for (int nf = 0; nf < 4; ++nf)
        acc[nf] = (f32x4){0.f, 0.f, 0.f, 0.f};

    const int cw = c0 + wv_ * 16;
    #pragma unroll
    for (int ks = 0; ks < 4; ++ks) {
        u16x8 b8[4];
        #pragma unroll
        for (int nf = 0; nf < 4; ++nf)
            b8[nf] = *(const u16x8*)&Ol[(nf * 16 + q16) * QS + ks * 32 + g * 8];
        u16x8 a8 = ldw8(&wo[(size_t)(cw + q16) * 128 + ks * 32 + g * 8]);
        #pragma unroll
        for (int nf = 0; nf < 4; ++nf)
            acc[nf] = mfma16(a8, b8[nf], acc[nf]);
    }

    float gm = gamma[0];
    #pragma unroll
    for (int i = 0; i < 4; ++i) {
        int c = cw + g * 4 + i;
        float bias = bo[c];
        #pragma unroll
        for (int nf = 0; nf < 4; ++nf) {
            int n = n0 + nf * 16 + q16;
            size_t idx = ((size_t)b * C_ + c) * N_ + n;
            out[idx] = gm * (acc[nf][i] + bias) + x[idx];
        }
    }
}

extern "C" void kernel_launch(void* const* d_in, const int* in_sizes, int n_in,
                              void* d_out, int out_size, void* d_ws, size_t ws_size,
                              hipStream_t stream) {
    const float* x     = (const float*)d_in[0];
    const float* wq    = (const float*)d_in[1];
    const float* bq    = (const float*)d_in[2];
    const float* wk    = (const float*)d_in[3];
    const float* bk    = (const float*)d_in[4];
    const float* wv    = (const float*)d_in[5];
    const float* bv    = (const float*)d_in[6];
    const float* wo    = (const float*)d_in[7];
    const float* bo    = (const float*)d_in[8];
    const float* gamma = (const float*)d_in[9];
    float* out = (float*)d_out;

    unsigned short* ws = (unsigned short*)d_ws;
    unsigned short* Qb = ws;                   // [B][N][RC] bf16 (also reused as Ob)
    unsigned short* Kb = Qb + 2097152;         // [B][N][RC] bf16
    unsigned short* Vt = Kb + 2097152;         // [B*128 tiles][128][36] image
    unsigned short* Ob = Qb;                   // alias: k_attn reads Q only in prologue

    dim3 g1(128, 4);
    k_qkv<<<g1, 256, 0, stream>>>(x, wq, wk, wv, bq, bk, bv, Qb, Kb, Vt);
    dim3 g2(64, 4);
    k_attn<<<g2, 1024, 0, stream>>>(Qb, Kb, Vt, Ob);
    dim3 g3(64, 4, 4);
    k_out<<<g3, 256, 0, stream>>>(Ob, wo, bo, x, gamma, out);
}